// Round 8
// baseline (577.680 us; speedup 1.0000x reference)
//
#include <hip/hip_runtime.h>
#include <hip/hip_bf16.h>
#include <hip/hip_cooperative_groups.h>

namespace cg = cooperative_groups;

typedef __bf16 bf16x8 __attribute__((ext_vector_type(8)));
typedef float f32x4 __attribute__((ext_vector_type(4)));

#define DEVI static __device__ __forceinline__

DEVI void load_lds16(const void* g, void* l) {
  __builtin_amdgcn_global_load_lds(
      (const __attribute__((address_space(1))) void*)g,
      (__attribute__((address_space(3))) void*)l, 16, 0, 0);
}

DEVI unsigned short f2b(float f) { return __bfloat16_as_ushort(__float2bfloat16(f)); }
DEVI float b2f(unsigned short u) {
  union { unsigned int i; float f; } c;
  c.i = ((unsigned int)u) << 16;
  return c.f;
}
DEVI float sigm(float x) { return 1.0f / (1.0f + __expf(-x)); }
DEVI float tanh_fast(float x) { return 2.0f / (1.0f + __expf(-2.0f * x)) - 1.0f; }

// involutive 16B-granule swizzle within a 32KB slot: XOR byte-bits 4-6 with bits 7-9.
DEVI int swz(int L) { return L ^ (((L >> 7) & 7) << 4); }

// ---------------------------------------------------------------- fused prep
// blocks [0,4096): cast x -> xb ; [4096,8192): perm-cast W -> Wbp ;
// [8192,12288): perm-cast U -> Ubp ; [12288,12304): bp = bW+bU (permuted)
__global__ __launch_bounds__(256) void prep_kernel(
    const float* __restrict__ x, const float* __restrict__ W,
    const float* __restrict__ U, const float* __restrict__ bW,
    const float* __restrict__ bU, unsigned short* __restrict__ xb,
    unsigned short* __restrict__ Wbp, unsigned short* __restrict__ Ubp,
    float* __restrict__ bp) {
  const int bid = blockIdx.x;
  if (bid < 4096) {
    const int i = bid * 256 + threadIdx.x;
    const float4 v = reinterpret_cast<const float4*>(x)[i];
    ushort4 o;
    o.x = f2b(v.x); o.y = f2b(v.y); o.z = f2b(v.z); o.w = f2b(v.w);
    reinterpret_cast<ushort4*>(xb)[i] = o;
  } else if (bid < 12288) {
    const bool isW = bid < 8192;
    const float* src = isW ? W : U;
    unsigned short* dst = isW ? Wbp : Ubp;
    const int i = (bid - (isW ? 4096 : 8192)) * 256 + threadIdx.x;
    const int r = i >> 8;
    const int cw = i & 255;
    const float4 v = reinterpret_cast<const float4*>(src)[i];
    const int rp = ((r & 1023) << 2) + (r >> 10);  // 4h+g
    ushort4 o;
    o.x = f2b(v.x); o.y = f2b(v.y); o.z = f2b(v.z); o.w = f2b(v.w);
    *reinterpret_cast<ushort4*>(&dst[(size_t)rp * 1024 + (cw << 2)]) = o;
  } else {
    const int i = (bid - 12288) * 256 + threadIdx.x;  // 0..4095
    const int h = i >> 2, g = i & 3;
    bp[i] = bW[g * 1024 + h] + bU[g * 1024 + h];
  }
}

// ---------------------------------------------------------------- persistent LSTM
// All 8 steps in one cooperative kernel; grid.sync() between steps.
// Per step: verified R7 256x256 GEMM K-loop (4 LDS slots x 32KB, counted vmcnt(8),
// XCD swizzle, 0 bank conflicts) + fused gates epilogue.
//   t=0: A=xb,  B=Wbp, mode0: s=acc+bp; write xpb; c_old=0
//   t=1..6:     B=Ubp, mode1: s=acc+xpb; c_old=ct;  write ct,ht
//   t=7:        B=Ubp, mode2: same but write fp32 (h,c) to out
__global__ __launch_bounds__(512, 2) void lstm_all(
    const unsigned short* __restrict__ xb,
    const unsigned short* __restrict__ Wbp,
    const unsigned short* __restrict__ Ubp,
    unsigned short* __restrict__ xpb,
    const float* __restrict__ bp,
    unsigned short* __restrict__ ct,
    unsigned short* __restrict__ htA,
    unsigned short* __restrict__ htB,
    float* __restrict__ out) {
  cg::grid_group grid = cg::this_grid();
  constexpr int K = 1024, N = 4096;
  constexpr int NPH = K / 32;  // 32 phases
  __shared__ unsigned char lds[256 * 528];  // 135168 B >= 4*32768 K-loop use

  const int tid = threadIdx.x;
  const int lane = tid & 63;
  const int wave = tid >> 6;
  const int wr = wave >> 2;  // 0..1 : M half (128 rows)
  const int wc = wave & 3;   // 0..3 : N quarter (64 cols)

  // XCD-aware block swizzle (nwg=256, divisible by 8)
  const int bid = blockIdx.x;
  const int sw = (bid & 7) * 32 + (bid >> 3);
  const int brow = (sw >> 4) * 256;
  const int bcol = (sw & 15) * 256;

  // staging geometry (swizzle via pre-permuted global source, rule #21)
  const int physA0 = tid * 16;
  const int physA1 = 8192 + tid * 16;
  const int physB0 = 16384 + tid * 16;
  const int physB1 = 24576 + tid * 16;
  const int LA0 = swz(physA0), LA1 = swz(physA1);
  const int LB0 = swz(physB0 - 16384), LB1 = swz(physB1 - 16384);
  // per-lane global offsets (row, kbyte) derived from swizzled logical offsets
  const size_t goA0 = (size_t)(brow + (LA0 >> 6)) * (K * 2) + (LA0 & 63);
  const size_t goA1 = (size_t)(brow + (LA1 >> 6)) * (K * 2) + (LA1 & 63);
  const size_t goB0 = (size_t)(bcol + (LB0 >> 6)) * (K * 2) + (LB0 & 63);
  const size_t goB1 = (size_t)(bcol + (LB1 >> 6)) * (K * 2) + (LB1 & 63);

  // fragment read offsets (slot-relative), swizzled
  const int s16 = (lane >> 4) * 16;
  int offA[8], offB[4];
#pragma unroll
  for (int m = 0; m < 8; ++m) {
    const int row = wr * 128 + m * 16 + (lane & 15);
    offA[m] = swz(row * 64 + s16);
  }
#pragma unroll
  for (int n = 0; n < 4; ++n) {
    const int row = wc * 64 + n * 16 + (lane & 15);
    offB[n] = 16384 + swz(row * 64 + s16);
  }

  const int hbase = bcol >> 2;

  for (int t = 0; t < 8; ++t) {
    const unsigned short* Amat = (t == 0) ? xb : ((t & 1) ? htA : htB);
    const unsigned short* Bmat = (t == 0) ? Wbp : Ubp;
    unsigned short* hout = (t & 1) ? htB : htA;
    const int mode = (t == 0) ? 0 : ((t == 7) ? 2 : 1);

    const unsigned char* pA0 = (const unsigned char*)Amat + goA0;
    const unsigned char* pA1 = (const unsigned char*)Amat + goA1;
    const unsigned char* pB0 = (const unsigned char*)Bmat + goB0;
    const unsigned char* pB1 = (const unsigned char*)Bmat + goB1;

    f32x4 acc[8][4] = {};

    auto STAGE = [&](int q) {
      unsigned char* sb = lds + (q & 3) * 32768;
      const size_t kb = (size_t)q * 64;
      load_lds16(pA0 + kb, sb + physA0);
      load_lds16(pA1 + kb, sb + physA1);
      load_lds16(pB0 + kb, sb + physB0);
      load_lds16(pB1 + kb, sb + physB1);
    };

    // prologue: 3 slots in flight (12 loads); vmcnt(8) retires slot 0's 4
    STAGE(0); STAGE(1); STAGE(2);
    asm volatile("s_waitcnt vmcnt(8)" ::: "memory");
    __builtin_amdgcn_s_barrier();
    __builtin_amdgcn_sched_barrier(0);

    for (int p = 0; p < NPH; ++p) {
      if (p + 3 < NPH) STAGE(p + 3);

      const unsigned char* sl = lds + (p & 3) * 32768;
      bf16x8 af[8], bf[4];
#pragma unroll
      for (int n = 0; n < 4; ++n) bf[n] = *reinterpret_cast<const bf16x8*>(sl + offB[n]);
#pragma unroll
      for (int m = 0; m < 8; ++m) af[m] = *reinterpret_cast<const bf16x8*>(sl + offA[m]);

      __builtin_amdgcn_s_setprio(1);
#pragma unroll
      for (int m = 0; m < 8; ++m)
#pragma unroll
        for (int n = 0; n < 4; ++n)
          acc[m][n] = __builtin_amdgcn_mfma_f32_16x16x32_bf16(af[m], bf[n], acc[m][n], 0, 0, 0);
      __builtin_amdgcn_s_setprio(0);

      if (p < NPH - 1) {
        if (p < NPH - 3)
          asm volatile("s_waitcnt vmcnt(8)" ::: "memory");
        else if (p == NPH - 3)
          asm volatile("s_waitcnt vmcnt(4)" ::: "memory");
        else
          asm volatile("s_waitcnt vmcnt(0)" ::: "memory");
        __builtin_amdgcn_s_barrier();
        __builtin_amdgcn_sched_barrier(0);
      }
    }

    // ---- epilogue: stage bf16 proj tile into LDS, padded row stride 264 elems
    __syncthreads();
    unsigned short* cs = (unsigned short*)lds;
    {
      const int c0 = wc * 64 + (lane & 15);
      const int r00 = wr * 128 + ((lane >> 4) << 2);
#pragma unroll
      for (int m = 0; m < 8; ++m)
#pragma unroll
        for (int n = 0; n < 4; ++n) {
          const int rr = r00 + m * 16;
          const int cc = c0 + n * 16;
#pragma unroll
          for (int r = 0; r < 4; ++r) cs[(rr + r) * 264 + cc] = f2b(acc[m][n][r]);
        }
    }
    __syncthreads();

    // ---- fused gates: 256 rows x 64 h per block
    if (mode == 0) {
#pragma unroll 4
      for (int j = 0; j < 32; ++j) {
        const int q = tid + (j << 9);
        const int row = q >> 6;
        const int hh = q & 63;
        const ushort4 pv = *reinterpret_cast<const ushort4*>(&cs[row * 264 + hh * 4]);
        const float4 bpv = *reinterpret_cast<const float4*>(&bp[bcol + hh * 4]);
        const int ci = (brow + row) * 1024 + hbase + hh;
        const float sf = b2f(pv.x) + bpv.x;
        const float si = b2f(pv.y) + bpv.y;
        const float so = b2f(pv.z) + bpv.z;
        const float sg = b2f(pv.w) + bpv.w;
        ushort4 xo;
        xo.x = f2b(sf); xo.y = f2b(si); xo.z = f2b(so); xo.w = f2b(sg);
        *reinterpret_cast<ushort4*>(&xpb[(size_t)(brow + row) * N + bcol + hh * 4]) = xo;
        const float ii = sigm(si);
        const float o = sigm(so);
        const float gg = tanh_fast(sg);
        const float c = ii * gg;  // f*0 + i*g
        const float h = o * tanh_fast(c);
        ct[ci] = f2b(c);
        hout[ci] = f2b(h);
      }
    } else if (mode == 1) {
#pragma unroll 4
      for (int j = 0; j < 32; ++j) {
        const int q = tid + (j << 9);
        const int row = q >> 6;
        const int hh = q & 63;
        const ushort4 pv = *reinterpret_cast<const ushort4*>(&cs[row * 264 + hh * 4]);
        const ushort4 xv = *reinterpret_cast<const ushort4*>(&xpb[(size_t)(brow + row) * N + bcol + hh * 4]);
        const int ci = (brow + row) * 1024 + hbase + hh;
        const float c_old = b2f(ct[ci]);
        const float f = sigm(b2f(pv.x) + b2f(xv.x));
        const float ii = sigm(b2f(pv.y) + b2f(xv.y));
        const float o = sigm(b2f(pv.z) + b2f(xv.z));
        const float gg = tanh_fast(b2f(pv.w) + b2f(xv.w));
        const float c = fmaf(f, c_old, ii * gg);
        const float h = o * tanh_fast(c);
        ct[ci] = f2b(c);
        hout[ci] = f2b(h);
      }
    } else {
#pragma unroll 4
      for (int j = 0; j < 32; ++j) {
        const int q = tid + (j << 9);
        const int row = q >> 6;
        const int hh = q & 63;
        const ushort4 pv = *reinterpret_cast<const ushort4*>(&cs[row * 264 + hh * 4]);
        const ushort4 xv = *reinterpret_cast<const ushort4*>(&xpb[(size_t)(brow + row) * N + bcol + hh * 4]);
        const int ci = (brow + row) * 1024 + hbase + hh;
        const float c_old = b2f(ct[ci]);
        const float f = sigm(b2f(pv.x) + b2f(xv.x));
        const float ii = sigm(b2f(pv.y) + b2f(xv.y));
        const float o = sigm(b2f(pv.z) + b2f(xv.z));
        const float gg = tanh_fast(b2f(pv.w) + b2f(xv.w));
        const float c = fmaf(f, c_old, ii * gg);
        const float h = o * tanh_fast(c);
        out[ci] = h;
        out[4194304 + ci] = c;
      }
    }

    if (t < 7) {
      // drain our VMEM (keeps the next step's vmcnt ledger exact), then grid barrier
      asm volatile("s_waitcnt vmcnt(0)" ::: "memory");
      grid.sync();
    }
  }
}

// ---------------------------------------------------------------- launch
extern "C" void kernel_launch(void* const* d_in, const int* in_sizes, int n_in,
                              void* d_out, int out_size, void* d_ws, size_t ws_size,
                              hipStream_t stream) {
  const float* x = (const float*)d_in[0];   // [4096,1024]
  const float* W = (const float*)d_in[1];   // [4096,1024]
  const float* bW = (const float*)d_in[2];  // [4096]
  const float* U = (const float*)d_in[3];   // [4096,1024]
  const float* bU = (const float*)d_in[4];  // [4096]
  float* out = (float*)d_out;

  char* w = (char*)d_ws;
  const size_t MB = 1ull << 20;
  unsigned short* xb = (unsigned short*)(w + 0 * MB);    // 8 MB
  unsigned short* Wbp = (unsigned short*)(w + 8 * MB);   // 8 MB (gate-interleaved)
  unsigned short* Ubp = (unsigned short*)(w + 16 * MB);  // 8 MB (gate-interleaved)
  unsigned short* xpb = (unsigned short*)(w + 24 * MB);  // 32 MB [B,4H] bf16 proj+bias
  unsigned short* ct = (unsigned short*)(w + 56 * MB);   // 8 MB bf16 state
  unsigned short* htA = (unsigned short*)(w + 64 * MB);  // 8 MB
  unsigned short* htB = (unsigned short*)(w + 72 * MB);  // 8 MB
  float* bp = (float*)(w + 80 * MB);                     // 16 KB

  prep_kernel<<<12304, 256, 0, stream>>>(x, W, U, bW, bU, xb, Wbp, Ubp, bp);

  void* args[] = {(void*)&xb, (void*)&Wbp, (void*)&Ubp, (void*)&xpb, (void*)&bp,
                  (void*)&ct, (void*)&htA, (void*)&htB, (void*)&out};
  hipLaunchCooperativeKernel((const void*)lstm_all, dim3(256), dim3(512), args, 0, stream);
}

// Round 9
// 387.376 us; speedup vs baseline: 1.4913x; 1.4913x over previous
//
#include <hip/hip_runtime.h>
#include <hip/hip_bf16.h>

typedef __bf16 bf16x8 __attribute__((ext_vector_type(8)));
typedef float f32x4 __attribute__((ext_vector_type(4)));

#define DEVI static __device__ __forceinline__

DEVI void load_lds16(const void* g, void* l) {
  __builtin_amdgcn_global_load_lds(
      (const __attribute__((address_space(1))) void*)g,
      (__attribute__((address_space(3))) void*)l, 16, 0, 0);
}

DEVI unsigned short f2b(float f) { return __bfloat16_as_ushort(__float2bfloat16(f)); }
DEVI float b2f(unsigned short u) {
  union { unsigned int i; float f; } c;
  c.i = ((unsigned int)u) << 16;
  return c.f;
}
DEVI float sigm(float x) { return 1.0f / (1.0f + __expf(-x)); }
DEVI float tanh_fast(float x) { return 2.0f / (1.0f + __expf(-2.0f * x)) - 1.0f; }

// involutive 16B-granule swizzle within a 32KB slot: XOR byte-bits 4-6 with bits 7-9.
DEVI int swz(int L) { return L ^ (((L >> 7) & 7) << 4); }

// ---------------------------------------------------------------- fused prep
// blocks [0,4096): cast x -> xb ; [4096,8192): perm-cast W -> Wbp ;
// [8192,12288): perm-cast U -> Ubp ; [12288,12304): bp = bW+bU (permuted)
__global__ __launch_bounds__(256) void prep_kernel(
    const float* __restrict__ x, const float* __restrict__ W,
    const float* __restrict__ U, const float* __restrict__ bW,
    const float* __restrict__ bU, unsigned short* __restrict__ xb,
    unsigned short* __restrict__ Wbp, unsigned short* __restrict__ Ubp,
    float* __restrict__ bp) {
  const int bid = blockIdx.x;
  if (bid < 4096) {
    const int i = bid * 256 + threadIdx.x;
    const float4 v = reinterpret_cast<const float4*>(x)[i];
    ushort4 o;
    o.x = f2b(v.x); o.y = f2b(v.y); o.z = f2b(v.z); o.w = f2b(v.w);
    reinterpret_cast<ushort4*>(xb)[i] = o;
  } else if (bid < 12288) {
    const bool isW = bid < 8192;
    const float* src = isW ? W : U;
    unsigned short* dst = isW ? Wbp : Ubp;
    const int i = (bid - (isW ? 4096 : 8192)) * 256 + threadIdx.x;
    const int r = i >> 8;
    const int cw = i & 255;
    const float4 v = reinterpret_cast<const float4*>(src)[i];
    const int rp = ((r & 1023) << 2) + (r >> 10);  // 4h+g
    ushort4 o;
    o.x = f2b(v.x); o.y = f2b(v.y); o.z = f2b(v.z); o.w = f2b(v.w);
    *reinterpret_cast<ushort4*>(&dst[(size_t)rp * 1024 + (cw << 2)]) = o;
  } else {
    const int i = (bid - 12288) * 256 + threadIdx.x;  // 0..4095
    const int h = i >> 2, g = i & 3;
    bp[i] = bW[g * 1024 + h] + bU[g * 1024 + h];
  }
}

// one K-phase: MFMA on current frags || ds_read next frags || stage slot p+4.
// af progressively overwritten (af[m] dead after its 4 MFMAs); bf double-buffered.
#define KPHASE(BFC, BFN, SLNXT, STAGEQ, DOSTAGE, WAITSTR, DOBAR)              \
  {                                                                           \
    if (DOSTAGE) STAGE(STAGEQ);                                               \
    const unsigned char* sln_ = (SLNXT);                                      \
    _Pragma("unroll") for (int n_ = 0; n_ < 4; ++n_)                          \
        BFN[n_] = *reinterpret_cast<const bf16x8*>(sln_ + offB[n_]);          \
    __builtin_amdgcn_s_setprio(1);                                            \
    _Pragma("unroll") for (int m_ = 0; m_ < 8; ++m_) {                        \
      _Pragma("unroll") for (int n_ = 0; n_ < 4; ++n_)                        \
          acc[m_][n_] = __builtin_amdgcn_mfma_f32_16x16x32_bf16(              \
              af[m_], BFC[n_], acc[m_][n_], 0, 0, 0);                         \
      af[m_] = *reinterpret_cast<const bf16x8*>(sln_ + offA[m_]);             \
    }                                                                         \
    __builtin_amdgcn_s_setprio(0);                                            \
    asm volatile(WAITSTR ::: "memory");                                       \
    __builtin_amdgcn_sched_barrier(0);                                        \
    if (DOBAR) {                                                              \
      __builtin_amdgcn_s_barrier();                                           \
      __builtin_amdgcn_sched_barrier(0);                                      \
    }                                                                         \
  }

// ---------------------------------------------------------------- GEMM 256x256 + fused LSTM gates
// proj = A[4096,1024] * Bm[4096,1024]^T (bf16 in, fp32 acc). 4 LDS slots x 32KB,
// counted vmcnt(8) (slots {p+2,p+3} always in flight), reg-dbuf pipeline:
// phase p: MFMA(frags p) || ds_read(frags p+1, slot p+1) || STAGE(p+4 -> slot p&3).
// Epilogue (verified R7): LDS-stage bf16 tile stride 264, fused gates by MODE.
template <int MODE>
__global__ __launch_bounds__(512, 2) void gemm256(
    const unsigned short* __restrict__ A,
    const unsigned short* __restrict__ Bm,
    const unsigned short* __restrict__ xpb_r,  // MID/LAST: [B,4H] bf16 (proj+bias)
    unsigned short* __restrict__ xpb_w,        // FIRST: write
    const float* __restrict__ bp,              // FIRST: [4H] combined bias
    unsigned short* __restrict__ ct,           // [B,H] bf16 state (rw)
    unsigned short* __restrict__ htout,        // [B,H] bf16 next-step input
    float* __restrict__ out) {                 // d_out when LAST
  constexpr int K = 1024, N = 4096;
  __shared__ unsigned char lds[256 * 528];  // 135168 B >= 4*32768 K-loop use

  const int tid = threadIdx.x;
  const int lane = tid & 63;
  const int wave = tid >> 6;
  const int wr = wave >> 2;  // 0..1 : M half (128 rows)
  const int wc = wave & 3;   // 0..3 : N quarter (64 cols)

  // XCD-aware block swizzle (nwg=256, divisible by 8)
  const int bid = blockIdx.x;
  const int sw = (bid & 7) * 32 + (bid >> 3);
  const int brow = (sw >> 4) * 256;
  const int bcol = (sw & 15) * 256;

  // staging geometry (swizzle via pre-permuted global source, rule #21)
  const int physA0 = tid * 16;
  const int physA1 = 8192 + tid * 16;
  const int physB0 = 16384 + tid * 16;
  const int physB1 = 24576 + tid * 16;
  const int LA0 = swz(physA0), LA1 = swz(physA1);
  const int LB0 = swz(physB0 - 16384), LB1 = swz(physB1 - 16384);
  const unsigned char* pA0 = (const unsigned char*)A + (size_t)(brow + (LA0 >> 6)) * (K * 2) + (LA0 & 63);
  const unsigned char* pA1 = (const unsigned char*)A + (size_t)(brow + (LA1 >> 6)) * (K * 2) + (LA1 & 63);
  const unsigned char* pB0 = (const unsigned char*)Bm + (size_t)(bcol + (LB0 >> 6)) * (K * 2) + (LB0 & 63);
  const unsigned char* pB1 = (const unsigned char*)Bm + (size_t)(bcol + (LB1 >> 6)) * (K * 2) + (LB1 & 63);

  // fragment read offsets (slot-relative), swizzled
  const int s16 = (lane >> 4) * 16;
  int offA[8], offB[4];
#pragma unroll
  for (int m = 0; m < 8; ++m) {
    const int row = wr * 128 + m * 16 + (lane & 15);
    offA[m] = swz(row * 64 + s16);
  }
#pragma unroll
  for (int n = 0; n < 4; ++n) {
    const int row = wc * 64 + n * 16 + (lane & 15);
    offB[n] = 16384 + swz(row * 64 + s16);
  }

  f32x4 acc[8][4] = {};
  bf16x8 af[8], bfE[4], bfO[4];

  auto STAGE = [&](int q) {
    unsigned char* sb = lds + (q & 3) * 32768;
    const size_t kb = (size_t)q * 64;
    load_lds16(pA0 + kb, sb + physA0);
    load_lds16(pA1 + kb, sb + physA1);
    load_lds16(pB0 + kb, sb + physB0);
    load_lds16(pB1 + kb, sb + physB1);
  };

  // prologue: 4 slots in flight (16 loads); vmcnt(8) retires slots 0,1
  STAGE(0); STAGE(1); STAGE(2); STAGE(3);
  asm volatile("s_waitcnt vmcnt(8)" ::: "memory");
  __builtin_amdgcn_s_barrier();
  // preload frags(0) from slot 0
#pragma unroll
  for (int n = 0; n < 4; ++n) bfE[n] = *reinterpret_cast<const bf16x8*>(lds + offB[n]);
#pragma unroll
  for (int m = 0; m < 8; ++m) af[m] = *reinterpret_cast<const bf16x8*>(lds + offA[m]);
  asm volatile("s_waitcnt lgkmcnt(0)" ::: "memory");
  __builtin_amdgcn_sched_barrier(0);
  __builtin_amdgcn_s_barrier();  // protect slot 0 from phase-0's STAGE(4)
  __builtin_amdgcn_sched_barrier(0);

  // phases 0..27 (uniform): stage p+4, vmcnt(8)
  for (int pp = 0; pp < 14; ++pp) {
    const int p = 2 * pp;
    const unsigned char* sl1 = lds + ((p + 1) & 3) * 32768;
    const unsigned char* sl2 = lds + ((p + 2) & 3) * 32768;
    KPHASE(bfE, bfO, sl1, p + 4, true, "s_waitcnt vmcnt(8) lgkmcnt(0)", true);
    KPHASE(bfO, bfE, sl2, p + 5, true, "s_waitcnt vmcnt(8) lgkmcnt(0)", true);
  }
  // phase 28: no stage, vmcnt(4) retires slot 30
  KPHASE(bfE, bfO, lds + (29 & 3) * 32768, 0, false, "s_waitcnt vmcnt(4) lgkmcnt(0)", true);
  // phase 29: no stage, vmcnt(0) retires slot 31
  KPHASE(bfO, bfE, lds + (30 & 3) * 32768, 0, false, "s_waitcnt vmcnt(0) lgkmcnt(0)", true);
  // phase 30: reads frags(31), lgkm only, no barrier (no pending LDS writes)
  KPHASE(bfE, bfO, lds + (31 & 3) * 32768, 0, false, "s_waitcnt lgkmcnt(0)", false);
  // phase 31: MFMA only
  __builtin_amdgcn_s_setprio(1);
#pragma unroll
  for (int m = 0; m < 8; ++m)
#pragma unroll
    for (int n = 0; n < 4; ++n)
      acc[m][n] = __builtin_amdgcn_mfma_f32_16x16x32_bf16(af[m], bfO[n], acc[m][n], 0, 0, 0);
  __builtin_amdgcn_s_setprio(0);

  // ---- epilogue: stage bf16 proj tile into LDS, padded row stride 264 elems
  __syncthreads();
  unsigned short* cs = (unsigned short*)lds;
  {
    const int c0 = wc * 64 + (lane & 15);
    const int r00 = wr * 128 + ((lane >> 4) << 2);
#pragma unroll
    for (int m = 0; m < 8; ++m)
#pragma unroll
      for (int n = 0; n < 4; ++n) {
        const int rr = r00 + m * 16;
        const int cc = c0 + n * 16;
#pragma unroll
        for (int r = 0; r < 4; ++r) cs[(rr + r) * 264 + cc] = f2b(acc[m][n][r]);
      }
  }
  __syncthreads();

  // ---- fused gates: 256 rows x 64 h per block
  const int hbase = bcol >> 2;
#pragma unroll 4
  for (int j = 0; j < 32; ++j) {
    const int q = tid + (j << 9);  // 0..16383
    const int row = q >> 6;
    const int hh = q & 63;
    const ushort4 pv = *reinterpret_cast<const ushort4*>(&cs[row * 264 + hh * 4]);
    const int ci = (brow + row) * 1024 + hbase + hh;
    float sf, si, so, sg;
    if constexpr (MODE == 0) {
      const float4 bpv = *reinterpret_cast<const float4*>(&bp[bcol + hh * 4]);
      sf = b2f(pv.x) + bpv.x;
      si = b2f(pv.y) + bpv.y;
      so = b2f(pv.z) + bpv.z;
      sg = b2f(pv.w) + bpv.w;
      ushort4 xo;
      xo.x = f2b(sf); xo.y = f2b(si); xo.z = f2b(so); xo.w = f2b(sg);
      *reinterpret_cast<ushort4*>(&xpb_w[(size_t)(brow + row) * N + bcol + hh * 4]) = xo;
    } else {
      const ushort4 xv = *reinterpret_cast<const ushort4*>(&xpb_r[(size_t)(brow + row) * N + bcol + hh * 4]);
      sf = b2f(pv.x) + b2f(xv.x);
      si = b2f(pv.y) + b2f(xv.y);
      so = b2f(pv.z) + b2f(xv.z);
      sg = b2f(pv.w) + b2f(xv.w);
    }
    const float c_old = (MODE == 0) ? 0.0f : b2f(ct[ci]);
    const float f = sigm(sf);
    const float ii = sigm(si);
    const float o = sigm(so);
    const float gg = tanh_fast(sg);
    const float c = fmaf(f, c_old, ii * gg);
    const float h = o * tanh_fast(c);
    if constexpr (MODE == 2) {
      out[ci] = h;
      out[4194304 + ci] = c;
    } else {
      ct[ci] = f2b(c);
      htout[ci] = f2b(h);
    }
  }
}

// ---------------------------------------------------------------- launch
extern "C" void kernel_launch(void* const* d_in, const int* in_sizes, int n_in,
                              void* d_out, int out_size, void* d_ws, size_t ws_size,
                              hipStream_t stream) {
  const float* x = (const float*)d_in[0];   // [4096,1024]
  const float* W = (const float*)d_in[1];   // [4096,1024]
  const float* bW = (const float*)d_in[2];  // [4096]
  const float* U = (const float*)d_in[3];   // [4096,1024]
  const float* bU = (const float*)d_in[4];  // [4096]
  float* out = (float*)d_out;

  char* w = (char*)d_ws;
  const size_t MB = 1ull << 20;
  unsigned short* xb = (unsigned short*)(w + 0 * MB);    // 8 MB
  unsigned short* Wbp = (unsigned short*)(w + 8 * MB);   // 8 MB (gate-interleaved)
  unsigned short* Ubp = (unsigned short*)(w + 16 * MB);  // 8 MB (gate-interleaved)
  unsigned short* xpb = (unsigned short*)(w + 24 * MB);  // 32 MB [B,4H] bf16 proj+bias
  unsigned short* ct = (unsigned short*)(w + 56 * MB);   // 8 MB bf16 state
  unsigned short* htA = (unsigned short*)(w + 64 * MB);  // 8 MB
  unsigned short* htB = (unsigned short*)(w + 72 * MB);  // 8 MB
  float* bp = (float*)(w + 80 * MB);                     // 16 KB

  prep_kernel<<<12304, 256, 0, stream>>>(x, W, U, bW, bU, xb, Wbp, Ubp, bp);

  // step 0: x-projection GEMM with fused gates (c0 = 0), writes xpb + ct + htA
  gemm256<0><<<256, 512, 0, stream>>>(xb, Wbp, nullptr, xpb, bp, ct, htA, nullptr);

  const unsigned short* hin = htA;
  unsigned short* hout = htB;
  for (int t = 1; t <= 6; ++t) {
    gemm256<1><<<256, 512, 0, stream>>>(hin, Ubp, xpb, nullptr, nullptr, ct, hout, nullptr);
    const unsigned short* tmp = hout;
    hout = (unsigned short*)hin;
    hin = tmp;
  }
  gemm256<2><<<256, 512, 0, stream>>>(hin, Ubp, xpb, nullptr, nullptr, ct, nullptr, out);
}